// Round 11
// baseline (1517.410 us; speedup 1.0000x reference)
//
#include <hip/hip_runtime.h>
#include <math.h>

typedef float nfloat4 __attribute__((ext_vector_type(4), aligned(16)));
typedef _Float16 h16;
typedef _Float16 h4 __attribute__((ext_vector_type(4)));   // 8B
typedef _Float16 h2 __attribute__((ext_vector_type(2)));   // 4B

__device__ __forceinline__ float softsign(float v) {
    float d = 1.0f + fabsf(v);
    return v * __builtin_amdgcn_rcpf(d);
}
__device__ __forceinline__ void nt_store4(float* p, float a, float b, float c, float d) {
    nfloat4 v; v.x = a; v.y = b; v.z = c; v.w = d;
    __builtin_nontemporal_store(v, (nfloat4*)p);
}
__device__ __forceinline__ int clamp63(int v) { return v < 0 ? 0 : (v > 63 ? 63 : v); }

// -------- first layer: 2 fp32 input channels -> 1 fp16 channel (round-8 verbatim) --------
__global__ __launch_bounds__(256) void conv_first(const float* __restrict__ in0,
                                                  const float* __restrict__ in1,
                                                  h16* __restrict__ out,
                                                  const float* __restrict__ w,
                                                  const float* __restrict__ bias) {
    int tid = blockIdx.x * 256 + threadIdx.x;
    int xq = (tid & 15) << 2;
    int y  = (tid >> 4) & 63;
    int z0 = ((tid >> 10) & 15) << 2;
    int b  = tid >> 14;
    const float* base0 = in0 + (size_t)b * 262144;
    const float* base1 = in1 + (size_t)b * 262144;

    float acc[4][4];
    #pragma unroll
    for (int i = 0; i < 4; ++i)
        #pragma unroll
        for (int j = 0; j < 4; ++j) acc[i][j] = 0.0f;

    #pragma unroll
    for (int zi = 0; zi < 6; ++zi) {
        int zin = clamp63(z0 + zi - 1);
        const float* p0 = base0 + zin * 4096;
        const float* p1 = base1 + zin * 4096;
        #pragma unroll
        for (int dy = 0; dy < 3; ++dy) {
            int yin = clamp63(y + dy - 1);
            const float* r0p = p0 + yin * 64;
            const float* r1p = p1 + yin * 64;
            float r0[6], r1[6];
            {
                const float4 v = *(const float4*)(r0p + xq);
                r0[0] = r0p[xq == 0 ? 0 : xq - 1];
                r0[1] = v.x; r0[2] = v.y; r0[3] = v.z; r0[4] = v.w;
                r0[5] = r0p[xq == 60 ? 63 : xq + 4];
            }
            {
                const float4 v = *(const float4*)(r1p + xq);
                r1[0] = r1p[xq == 0 ? 0 : xq - 1];
                r1[1] = v.x; r1[2] = v.y; r1[3] = v.z; r1[4] = v.w;
                r1[5] = r1p[xq == 60 ? 63 : xq + 4];
            }
            #pragma unroll
            for (int dz = 0; dz < 3; ++dz) {
                int zo = zi - dz;
                if (zo >= 0 && zo < 4) {
                    #pragma unroll
                    for (int dx = 0; dx < 3; ++dx) {
                        float w0v = w[dz * 9 + dy * 3 + dx];
                        float w1v = w[27 + dz * 9 + dy * 3 + dx];
                        #pragma unroll
                        for (int xx = 0; xx < 4; ++xx) {
                            acc[zo][xx] = fmaf(w0v, r0[xx + dx], acc[zo][xx]);
                            acc[zo][xx] = fmaf(w1v, r1[xx + dx], acc[zo][xx]);
                        }
                    }
                }
            }
        }
    }
    float bv = *bias;
    h16* obase = out + (size_t)b * 262144 + (size_t)z0 * 4096 + y * 64 + xq;
    #pragma unroll
    for (int zo = 0; zo < 4; ++zo) {
        h4 o;
        o.x = (h16)softsign(acc[zo][0] + bv);
        o.y = (h16)softsign(acc[zo][1] + bv);
        o.z = (h16)softsign(acc[zo][2] + bv);
        o.w = (h16)softsign(acc[zo][3] + bv);
        *(h4*)(obase + zo * 4096) = o;
    }
}

// ---- fused PAIR of middle layers, fp16: output tile 64x * 8y * 8z per block ----
// LDS: staged sA 12 planes x 12 rows x 68 halves = 19.6 KB
//      intermediate sM 10 planes x 10 rows x 68 halves = 13.6 KB  -> 33.2 KB
// => 4 blocks/CU, grid 1024 (8 XCD z-slabs x 16 batches x 8 y-tiles) fully
// co-resident in ONE scheduling round (fixes round-2's 2-round ramp penalty).
// EDGE RULE (hardware-verified in round 2): intermediate slot (pi,r) computed
// at UNCLAMPED coord (z0-1+pi, y0-1+r); its input is staged slot (pi+dz, r+dy)
// exactly [staged pa holds clamp(z0-2+pa)]. Volume-face slots hold extrapolated
// values never read, because phase C uses the clamped slot lookup:
//   plane slot for virtual k: clamp63(z0+zh+k-1) - z0 + 1
//   row   slot:               clamp63(y0+yloc+dy-1) - y0 + 1
// fp16 x-layout (round-8 verified): UNSHIFTED, dup of x=63 at positions 64,65;
// x-1 read as hi half of aligned h2 at xq-2 (select for lane 0).
#define SPLH 816   // 12*68
#define MPLH 680   // 10*68

__global__ __launch_bounds__(256, 4) void conv_mid2(const h16* __restrict__ in,
                                                    h16* __restrict__ out,
                                                    const float* __restrict__ w1,
                                                    const float* __restrict__ w2,
                                                    const float* __restrict__ b1,
                                                    const float* __restrict__ b2) {
    __shared__ h16 sA[12 * SPLH];
    __shared__ h16 sM[10 * MPLH];

    int blk = blockIdx.x;
    int xcd = blk & 7;
    int j   = blk >> 3;                // 0..127
    int b   = j & 15;
    int y0  = ((j >> 4) & 7) << 3;     // 0,8,...,56
    int z0  = xcd << 3;                // XCD-affine z-slab

    int t = threadIdx.x;
    int l = t & 15;
    int g = t >> 4;

    const size_t bofs = (size_t)b * 262144;
    const h16* base = in + bofs;

    // ---- phase A: stage 144 rows (12 planes x 12 rows) = 9 iters x 16 rows ----
    {
        h16* lrows[9]; h4 mv[9]; h16 tv[9];
        #pragma unroll
        for (int it = 0; it < 9; ++it) {
            int rid = it * 16 + g;                 // 0..143, all valid
            int pa = rid / 12;
            int pr = rid - pa * 12;
            const h16* grow = base + clamp63(z0 - 2 + pa) * 4096 + clamp63(y0 - 2 + pr) * 64;
            lrows[it] = &sA[pa * SPLH + pr * 68];
            mv[it] = *(const h4*)(grow + 4 * l);   // 8B-aligned
            tv[it] = grow[63];
        }
        #pragma unroll
        for (int it = 0; it < 9; ++it) {
            *(h4*)(lrows[it] + 4 * l) = mv[it];
            if (l == 15) { h2 d; d.x = tv[it]; d.y = tv[it]; *(h2*)(lrows[it] + 64) = d; }
        }
    }
    __syncthreads();

    // ---- phase B: layer 1 -> sM; thread = (x-quad, row), 10 z-planes each ----
    {
        int l2 = t & 15;
        int r  = t >> 4;               // 0..15; rows 10..15 idle
        if (r < 10) {
            float wv1[27];
            #pragma unroll
            for (int i = 0; i < 27; ++i) wv1[i] = w1[i];
            float b1v = *b1;
            int xq2 = l2 << 2;

            float acc[10][4];
            #pragma unroll
            for (int i = 0; i < 10; ++i)
                #pragma unroll
                for (int k = 0; k < 4; ++k) acc[i][k] = b1v;

            #pragma unroll
            for (int pa = 0; pa < 12; ++pa) {
                #pragma unroll
                for (int dy = 0; dy < 3; ++dy) {
                    const h16* lrow = &sA[pa * SPLH + (r + dy) * 68];
                    h4 v  = *(const h4*)(lrow + xq2);
                    h2 v2 = *(const h2*)(lrow + xq2 + 4);
                    h2 vf = *(const h2*)(lrow + (xq2 == 0 ? 0 : xq2 - 2));
                    float rr[6];
                    rr[0] = (xq2 == 0) ? (float)v.x : (float)vf.y;
                    rr[1] = (float)v.x; rr[2] = (float)v.y; rr[3] = (float)v.z;
                    rr[4] = (float)v.w; rr[5] = (float)v2.x;
                    #pragma unroll
                    for (int dz = 0; dz < 3; ++dz) {
                        int pi = pa - dz;
                        if (pi >= 0 && pi < 10) {
                            #pragma unroll
                            for (int dx = 0; dx < 3; ++dx) {
                                float ww = wv1[dz * 9 + dy * 3 + dx];
                                #pragma unroll
                                for (int xx = 0; xx < 4; ++xx)
                                    acc[pi][xx] = fmaf(ww, rr[xx + dx], acc[pi][xx]);
                            }
                        }
                    }
                }
            }
            #pragma unroll
            for (int pi = 0; pi < 10; ++pi) {
                h4 o;
                o.x = (h16)softsign(acc[pi][0]);
                o.y = (h16)softsign(acc[pi][1]);
                o.z = (h16)softsign(acc[pi][2]);
                o.w = (h16)softsign(acc[pi][3]);
                h16* orow = &sM[pi * MPLH + r * 68];
                *(h4*)(orow + xq2) = o;
                if (l2 == 15) { h2 d; d.x = o.w; d.y = o.w; *(h2*)(orow + 64) = d; }
            }
        }
    }
    __syncthreads();

    // ---- phase C: layer 2 -> global; thread = (xq, yloc, z-half); 4x*1y*4z ----
    {
        float wv2[27];
        #pragma unroll
        for (int i = 0; i < 27; ++i) wv2[i] = w2[i];
        float b2v = *b2;

        int xq   = l << 2;
        int yloc = g & 7;
        int zh   = (g >> 3) << 2;      // 0 or 4

        int zsl[6];
        #pragma unroll
        for (int k = 0; k < 6; ++k) zsl[k] = clamp63(z0 + zh + k - 1) - z0 + 1;
        int sc[3];
        #pragma unroll
        for (int dy = 0; dy < 3; ++dy) sc[dy] = clamp63(y0 + yloc + dy - 1) - y0 + 1;

        float acc[4][4];
        #pragma unroll
        for (int i = 0; i < 4; ++i)
            #pragma unroll
            for (int k = 0; k < 4; ++k) acc[i][k] = b2v;

        #pragma unroll
        for (int pp = 0; pp < 6; ++pp) {
            const h16* pl = &sM[zsl[pp] * MPLH];
            #pragma unroll
            for (int dy = 0; dy < 3; ++dy) {
                const h16* lrow = pl + sc[dy] * 68;
                h4 v  = *(const h4*)(lrow + xq);
                h2 v2 = *(const h2*)(lrow + xq + 4);
                h2 vf = *(const h2*)(lrow + (xq == 0 ? 0 : xq - 2));
                float rr[6];
                rr[0] = (xq == 0) ? (float)v.x : (float)vf.y;
                rr[1] = (float)v.x; rr[2] = (float)v.y; rr[3] = (float)v.z;
                rr[4] = (float)v.w; rr[5] = (float)v2.x;
                #pragma unroll
                for (int dz = 0; dz < 3; ++dz) {
                    int zz = pp - dz;
                    if (zz >= 0 && zz < 4) {
                        #pragma unroll
                        for (int dx = 0; dx < 3; ++dx) {
                            float ww = wv2[dz * 9 + dy * 3 + dx];
                            #pragma unroll
                            for (int xx = 0; xx < 4; ++xx)
                                acc[zz][xx] = fmaf(ww, rr[xx + dx], acc[zz][xx]);
                        }
                    }
                }
            }
        }

        int y = y0 + yloc;
        h16* obase = out + bofs + (size_t)(z0 + zh) * 4096 + y * 64 + xq;
        #pragma unroll
        for (int zz = 0; zz < 4; ++zz) {
            h4 o;
            o.x = (h16)softsign(acc[zz][0]);
            o.y = (h16)softsign(acc[zz][1]);
            o.z = (h16)softsign(acc[zz][2]);
            o.w = (h16)softsign(acc[zz][3]);
            *(h4*)(obase + zz * 4096) = o;   // normal store: stays in local-XCD L2
        }
    }
}

// -------- last layer: fp16 in -> 3 fp32 channels + strided downsamples (round-8 verbatim) --------
__device__ __forceinline__ void load_row6h(const h16* __restrict__ row, int x0, float r[6]) {
    h4 v = *(const h4*)(row + x0);
    r[0] = (float)row[x0 == 0 ? 0 : x0 - 1];
    r[1] = (float)v.x; r[2] = (float)v.y; r[3] = (float)v.z; r[4] = (float)v.w;
    r[5] = (float)row[x0 == 60 ? 63 : x0 + 4];
}

__global__ __launch_bounds__(256) void conv_last(const h16* __restrict__ in,
                                                 float* __restrict__ out,
                                                 const float* __restrict__ w,
                                                 const float* __restrict__ bias) {
    int tid = blockIdx.x * 256 + threadIdx.x;
    int xq = (tid & 15) << 2;
    int y  = (tid >> 4) & 63;
    int z0 = ((tid >> 10) & 15) << 2;
    int b  = tid >> 14;
    const h16* base = in + (size_t)b * 262144;

    float acc[4][3][4];
    #pragma unroll
    for (int i = 0; i < 4; ++i)
        #pragma unroll
        for (int c = 0; c < 3; ++c)
            #pragma unroll
            for (int j = 0; j < 4; ++j) acc[i][c][j] = 0.0f;

    #pragma unroll
    for (int zi = 0; zi < 6; ++zi) {
        int zin = clamp63(z0 + zi - 1);
        const h16* plane = base + zin * 4096;
        #pragma unroll
        for (int dy = 0; dy < 3; ++dy) {
            int yin = clamp63(y + dy - 1);
            float r[6];
            load_row6h(plane + yin * 64, xq, r);
            #pragma unroll
            for (int dz = 0; dz < 3; ++dz) {
                int zo = zi - dz;
                if (zo >= 0 && zo < 4) {
                    #pragma unroll
                    for (int c = 0; c < 3; ++c) {
                        #pragma unroll
                        for (int dx = 0; dx < 3; ++dx) {
                            float wc = w[c * 27 + dz * 9 + dy * 3 + dx];
                            #pragma unroll
                            for (int xx = 0; xx < 4; ++xx)
                                acc[zo][c][xx] = fmaf(wc, r[xx + dx], acc[zo][c][xx]);
                        }
                    }
                }
            }
        }
    }

    float* r64 = out;
    float* r32 = out + 12582912;
    float* r16 = r32 + 1572864;
    float* r8  = r16 + 196608;

    float vals[4][3][4];
    #pragma unroll
    for (int zo = 0; zo < 4; ++zo)
        #pragma unroll
        for (int c = 0; c < 3; ++c) {
            float bv = bias[c];
            #pragma unroll
            for (int xx = 0; xx < 4; ++xx)
                vals[zo][c][xx] = softsign(acc[zo][c][xx] + bv);
        }

    #pragma unroll
    for (int c = 0; c < 3; ++c) {
        float* cb = r64 + ((size_t)b * 3 + c) * 262144 + (size_t)z0 * 4096 + y * 64 + xq;
        #pragma unroll
        for (int zo = 0; zo < 4; ++zo) {
            nt_store4(cb + zo * 4096,
                      vals[zo][c][0], vals[zo][c][1], vals[zo][c][2], vals[zo][c][3]);
        }
    }
    if ((y & 1) == 0) {
        #pragma unroll
        for (int c = 0; c < 3; ++c) {
            size_t cb = ((size_t)b * 3 + c) * 32768 + (size_t)(y >> 1) * 32;
            #pragma unroll
            for (int zo = 0; zo < 4; zo += 2) {
                size_t zb = cb + (size_t)((z0 + zo) >> 1) * 1024;
                __builtin_nontemporal_store(vals[zo][c][0], r32 + zb + ((xq + 0) >> 1));
                __builtin_nontemporal_store(vals[zo][c][2], r32 + zb + ((xq + 2) >> 1));
            }
        }
    }
    if ((y & 3) == 0) {
        #pragma unroll
        for (int c = 0; c < 3; ++c) {
            __builtin_nontemporal_store(vals[0][c][0],
                r16 + ((size_t)b * 3 + c) * 4096 + (size_t)(z0 >> 2) * 256 + (y >> 2) * 16 + (xq >> 2));
        }
    }
    if ((y & 7) == 0 && (z0 & 7) == 0 && (xq & 7) == 0) {
        #pragma unroll
        for (int c = 0; c < 3; ++c) {
            __builtin_nontemporal_store(vals[0][c][0],
                r8 + ((size_t)b * 3 + c) * 512 + (size_t)(z0 >> 3) * 64 + (y >> 3) * 8 + (xq >> 3));
        }
    }
}

extern "C" void kernel_launch(void* const* d_in, const int* in_sizes, int n_in,
                              void* d_out, int out_size, void* d_ws, size_t ws_size,
                              hipStream_t stream) {
    const float* preop = (const float*)d_in[0];
    const float* intra = (const float*)d_in[1];
    const float* w0    = (const float*)d_in[2];
    const float* b0p   = (const float*)d_in[3];
    const float* wsp   = (const float*)d_in[4];
    const float* bsp   = (const float*)d_in[5];
    const float* wX    = (const float*)d_in[6];
    const float* bX    = (const float*)d_in[7];
    float* out = (float*)d_out;

    h16* buf0 = (h16*)d_ws;          // 8.4 MB fp16 ping
    h16* buf1 = (h16*)out;           // fp16 pong inside the (larger) output buffer;
                                     // conv_last reads buf0 only; out fully overwritten.

    conv_first<<<dim3(1024), dim3(256), 0, stream>>>(preop, intra, buf0, w0, b0p);
    // 100 mids = 50 fused pairs. k even: buf0->buf1, k odd: buf1->buf0; k=49 -> buf0.
    for (int k = 0; k < 50; ++k) {
        const h16* src = (k & 1) ? buf1 : buf0;
        h16* dst       = (k & 1) ? buf0 : buf1;
        conv_mid2<<<dim3(1024), dim3(256), 0, stream>>>(src, dst,
                                                        wsp + (2 * k) * 27,
                                                        wsp + (2 * k + 1) * 27,
                                                        bsp + 2 * k,
                                                        bsp + 2 * k + 1);
    }
    conv_last<<<dim3(1024), dim3(256), 0, stream>>>(buf0, out, wX, bX);
}

// Round 12
// 922.896 us; speedup vs baseline: 1.6442x; 1.6442x over previous
//
#include <hip/hip_runtime.h>
#include <math.h>

typedef float nfloat4 __attribute__((ext_vector_type(4), aligned(16)));
typedef _Float16 h16;
typedef _Float16 h4 __attribute__((ext_vector_type(4)));   // 8B
typedef _Float16 h2 __attribute__((ext_vector_type(2)));   // 4B

__device__ __forceinline__ float softsign(float v) {
    float d = 1.0f + fabsf(v);
    return v * __builtin_amdgcn_rcpf(d);
}
__device__ __forceinline__ void nt_store4(float* p, float a, float b, float c, float d) {
    nfloat4 v; v.x = a; v.y = b; v.z = c; v.w = d;
    __builtin_nontemporal_store(v, (nfloat4*)p);
}
__device__ __forceinline__ int clamp63(int v) { return v < 0 ? 0 : (v > 63 ? 63 : v); }

// -------- first layer: 2 fp32 input channels -> 1 fp16 channel (round-8 verbatim) --------
__global__ __launch_bounds__(256) void conv_first(const float* __restrict__ in0,
                                                  const float* __restrict__ in1,
                                                  h16* __restrict__ out,
                                                  const float* __restrict__ w,
                                                  const float* __restrict__ bias) {
    int tid = blockIdx.x * 256 + threadIdx.x;
    int xq = (tid & 15) << 2;
    int y  = (tid >> 4) & 63;
    int z0 = ((tid >> 10) & 15) << 2;
    int b  = tid >> 14;
    const float* base0 = in0 + (size_t)b * 262144;
    const float* base1 = in1 + (size_t)b * 262144;

    float acc[4][4];
    #pragma unroll
    for (int i = 0; i < 4; ++i)
        #pragma unroll
        for (int j = 0; j < 4; ++j) acc[i][j] = 0.0f;

    #pragma unroll
    for (int zi = 0; zi < 6; ++zi) {
        int zin = clamp63(z0 + zi - 1);
        const float* p0 = base0 + zin * 4096;
        const float* p1 = base1 + zin * 4096;
        #pragma unroll
        for (int dy = 0; dy < 3; ++dy) {
            int yin = clamp63(y + dy - 1);
            const float* r0p = p0 + yin * 64;
            const float* r1p = p1 + yin * 64;
            float r0[6], r1[6];
            {
                const float4 v = *(const float4*)(r0p + xq);
                r0[0] = r0p[xq == 0 ? 0 : xq - 1];
                r0[1] = v.x; r0[2] = v.y; r0[3] = v.z; r0[4] = v.w;
                r0[5] = r0p[xq == 60 ? 63 : xq + 4];
            }
            {
                const float4 v = *(const float4*)(r1p + xq);
                r1[0] = r1p[xq == 0 ? 0 : xq - 1];
                r1[1] = v.x; r1[2] = v.y; r1[3] = v.z; r1[4] = v.w;
                r1[5] = r1p[xq == 60 ? 63 : xq + 4];
            }
            #pragma unroll
            for (int dz = 0; dz < 3; ++dz) {
                int zo = zi - dz;
                if (zo >= 0 && zo < 4) {
                    #pragma unroll
                    for (int dx = 0; dx < 3; ++dx) {
                        float w0v = w[dz * 9 + dy * 3 + dx];
                        float w1v = w[27 + dz * 9 + dy * 3 + dx];
                        #pragma unroll
                        for (int xx = 0; xx < 4; ++xx) {
                            acc[zo][xx] = fmaf(w0v, r0[xx + dx], acc[zo][xx]);
                            acc[zo][xx] = fmaf(w1v, r1[xx + dx], acc[zo][xx]);
                        }
                    }
                }
            }
        }
    }
    float bv = *bias;
    h16* obase = out + (size_t)b * 262144 + (size_t)z0 * 4096 + y * 64 + xq;
    #pragma unroll
    for (int zo = 0; zo < 4; ++zo) {
        h4 o;
        o.x = (h16)softsign(acc[zo][0] + bv);
        o.y = (h16)softsign(acc[zo][1] + bv);
        o.z = (h16)softsign(acc[zo][2] + bv);
        o.w = (h16)softsign(acc[zo][3] + bv);
        *(h4*)(obase + zo * 4096) = o;
    }
}

// ---- middle layer, fp16 storage / fp32 math: 64x * 8y * 8z per block ----
// Round-8 verified structure (944.6 us): LDS 13.6 KB, grid 1024 = 4 blocks/CU
// (8 XCD z-slabs x 16 batches x 8 y-tiles), thread = (4x,1y,4z).
// CHANGE vs round 8: the tail load tv = grow[63] was redundant — for the only
// lanes that consume it (l==15), mv.w IS grow[63] (h4 covers halves 60..63).
// Removing it halves staging VMEM instructions (14 -> 7 per thread) in the
// ramp-critical phase; semantics bit-identical.
#define LROWH   68
#define LPLANEH 680    // 10*68

__global__ __launch_bounds__(256, 4) void conv_mid(const h16* __restrict__ in,
                                                   h16* __restrict__ out,
                                                   const float* __restrict__ w,
                                                   const float* __restrict__ bias) {
    __shared__ h16 lds[10 * LPLANEH];

    int blk = blockIdx.x;
    int xcd = blk & 7;
    int j   = blk >> 3;                // 0..127
    int b   = j & 15;
    int y0  = ((j >> 4) & 7) << 3;     // 0,8,...,56
    int z0  = xcd << 3;                // XCD-affine z-slab

    int t = threadIdx.x;
    int l = t & 15;
    int g = t >> 4;

    const h16* base = in + (size_t)b * 262144;

    float wv[27];
    #pragma unroll
    for (int i = 0; i < 27; ++i) wv[i] = w[i];
    float bv = *bias;

    // ---- stage 100 rows (10 planes x 10 rows); 7 h4 loads/thread, no tail loads ----
    {
        h16* lrows[7]; h4 mv[7];
        #pragma unroll
        for (int it = 0; it < 7; ++it) {
            int rid = it * 16 + g;                 // 0..111 (100..111 dummy)
            int pa = rid / 10;
            pa = pa > 9 ? 9 : pa;                  // dummy rows: clamp-safe addr
            int pr = rid - pa * 10;
            pr = pr > 9 ? 9 : pr;
            const h16* grow = base + clamp63(z0 - 1 + pa) * 4096 + clamp63(y0 - 1 + pr) * 64;
            lrows[it] = &lds[pa * LPLANEH + pr * LROWH];
            mv[it] = *(const h4*)(grow + 4 * l);   // 8B-aligned; l==15 holds x=60..63
        }
        #pragma unroll
        for (int it = 0; it < 7; ++it) {
            int rid = it * 16 + g;
            if (rid < 100) {
                *(h4*)(lrows[it] + 4 * l) = mv[it];
                if (l == 15) {                      // dup x=63 into slots 64,65
                    h2 d; d.x = mv[it].w; d.y = mv[it].w;
                    *(h2*)(lrows[it] + 64) = d;
                }
            }
        }
    }
    __syncthreads();

    // ---- compute (fp32 math): 4z x 1y x 4x per thread (round-8 verbatim) ----
    int xq   = l << 2;
    int yloc = g & 7;              // 0..7; LDS rows yloc..yloc+2 = y-1,y,y+1
    int zh   = (g >> 3) << 2;      // 0 or 4

    float acc[4][4];
    #pragma unroll
    for (int i = 0; i < 4; ++i)
        #pragma unroll
        for (int k = 0; k < 4; ++k) acc[i][k] = 0.0f;

    #pragma unroll
    for (int pp = 0; pp < 6; ++pp) {
        const h16* pl = &lds[(zh + pp) * LPLANEH];
        #pragma unroll
        for (int dy = 0; dy < 3; ++dy) {
            const h16* lrow = pl + (yloc + dy) * LROWH;
            h4 v  = *(const h4*)(lrow + xq);
            h2 v2 = *(const h2*)(lrow + xq + 4);
            h2 vf = *(const h2*)(lrow + (xq == 0 ? 0 : xq - 2));
            float r[6];
            r[0] = (xq == 0) ? (float)v.x : (float)vf.y;
            r[1] = (float)v.x; r[2] = (float)v.y; r[3] = (float)v.z;
            r[4] = (float)v.w; r[5] = (float)v2.x;
            #pragma unroll
            for (int dz = 0; dz < 3; ++dz) {
                int zz = pp - dz;
                if (zz >= 0 && zz < 4) {
                    #pragma unroll
                    for (int dx = 0; dx < 3; ++dx) {
                        float ww = wv[dz * 9 + dy * 3 + dx];
                        #pragma unroll
                        for (int xx = 0; xx < 4; ++xx)
                            acc[zz][xx] = fmaf(ww, r[xx + dx], acc[zz][xx]);
                    }
                }
            }
        }
    }

    int y = y0 + yloc;
    h16* obase = out + (size_t)b * 262144 + (size_t)(z0 + zh) * 4096 + y * 64 + xq;
    #pragma unroll
    for (int zz = 0; zz < 4; ++zz) {
        h4 o;
        o.x = (h16)softsign(acc[zz][0] + bv);
        o.y = (h16)softsign(acc[zz][1] + bv);
        o.z = (h16)softsign(acc[zz][2] + bv);
        o.w = (h16)softsign(acc[zz][3] + bv);
        *(h4*)(obase + zz * 4096) = o;   // normal store: stays in local-XCD L2
    }
}

// -------- last layer: fp16 in -> 3 fp32 channels + strided downsamples (round-8 verbatim) --------
__device__ __forceinline__ void load_row6h(const h16* __restrict__ row, int x0, float r[6]) {
    h4 v = *(const h4*)(row + x0);
    r[0] = (float)row[x0 == 0 ? 0 : x0 - 1];
    r[1] = (float)v.x; r[2] = (float)v.y; r[3] = (float)v.z; r[4] = (float)v.w;
    r[5] = (float)row[x0 == 60 ? 63 : x0 + 4];
}

__global__ __launch_bounds__(256) void conv_last(const h16* __restrict__ in,
                                                 float* __restrict__ out,
                                                 const float* __restrict__ w,
                                                 const float* __restrict__ bias) {
    int tid = blockIdx.x * 256 + threadIdx.x;
    int xq = (tid & 15) << 2;
    int y  = (tid >> 4) & 63;
    int z0 = ((tid >> 10) & 15) << 2;
    int b  = tid >> 14;
    const h16* base = in + (size_t)b * 262144;

    float acc[4][3][4];
    #pragma unroll
    for (int i = 0; i < 4; ++i)
        #pragma unroll
        for (int c = 0; c < 3; ++c)
            #pragma unroll
            for (int j = 0; j < 4; ++j) acc[i][c][j] = 0.0f;

    #pragma unroll
    for (int zi = 0; zi < 6; ++zi) {
        int zin = clamp63(z0 + zi - 1);
        const h16* plane = base + zin * 4096;
        #pragma unroll
        for (int dy = 0; dy < 3; ++dy) {
            int yin = clamp63(y + dy - 1);
            float r[6];
            load_row6h(plane + yin * 64, xq, r);
            #pragma unroll
            for (int dz = 0; dz < 3; ++dz) {
                int zo = zi - dz;
                if (zo >= 0 && zo < 4) {
                    #pragma unroll
                    for (int c = 0; c < 3; ++c) {
                        #pragma unroll
                        for (int dx = 0; dx < 3; ++dx) {
                            float wc = w[c * 27 + dz * 9 + dy * 3 + dx];
                            #pragma unroll
                            for (int xx = 0; xx < 4; ++xx)
                                acc[zo][c][xx] = fmaf(wc, r[xx + dx], acc[zo][c][xx]);
                        }
                    }
                }
            }
        }
    }

    float* r64 = out;
    float* r32 = out + 12582912;
    float* r16 = r32 + 1572864;
    float* r8  = r16 + 196608;

    float vals[4][3][4];
    #pragma unroll
    for (int zo = 0; zo < 4; ++zo)
        #pragma unroll
        for (int c = 0; c < 3; ++c) {
            float bv = bias[c];
            #pragma unroll
            for (int xx = 0; xx < 4; ++xx)
                vals[zo][c][xx] = softsign(acc[zo][c][xx] + bv);
        }

    #pragma unroll
    for (int c = 0; c < 3; ++c) {
        float* cb = r64 + ((size_t)b * 3 + c) * 262144 + (size_t)z0 * 4096 + y * 64 + xq;
        #pragma unroll
        for (int zo = 0; zo < 4; ++zo) {
            nt_store4(cb + zo * 4096,
                      vals[zo][c][0], vals[zo][c][1], vals[zo][c][2], vals[zo][c][3]);
        }
    }
    if ((y & 1) == 0) {
        #pragma unroll
        for (int c = 0; c < 3; ++c) {
            size_t cb = ((size_t)b * 3 + c) * 32768 + (size_t)(y >> 1) * 32;
            #pragma unroll
            for (int zo = 0; zo < 4; zo += 2) {
                size_t zb = cb + (size_t)((z0 + zo) >> 1) * 1024;
                __builtin_nontemporal_store(vals[zo][c][0], r32 + zb + ((xq + 0) >> 1));
                __builtin_nontemporal_store(vals[zo][c][2], r32 + zb + ((xq + 2) >> 1));
            }
        }
    }
    if ((y & 3) == 0) {
        #pragma unroll
        for (int c = 0; c < 3; ++c) {
            __builtin_nontemporal_store(vals[0][c][0],
                r16 + ((size_t)b * 3 + c) * 4096 + (size_t)(z0 >> 2) * 256 + (y >> 2) * 16 + (xq >> 2));
        }
    }
    if ((y & 7) == 0 && (z0 & 7) == 0 && (xq & 7) == 0) {
        #pragma unroll
        for (int c = 0; c < 3; ++c) {
            __builtin_nontemporal_store(vals[0][c][0],
                r8 + ((size_t)b * 3 + c) * 512 + (size_t)(z0 >> 3) * 64 + (y >> 3) * 8 + (xq >> 3));
        }
    }
}

extern "C" void kernel_launch(void* const* d_in, const int* in_sizes, int n_in,
                              void* d_out, int out_size, void* d_ws, size_t ws_size,
                              hipStream_t stream) {
    const float* preop = (const float*)d_in[0];
    const float* intra = (const float*)d_in[1];
    const float* w0    = (const float*)d_in[2];
    const float* b0p   = (const float*)d_in[3];
    const float* wsp   = (const float*)d_in[4];
    const float* bsp   = (const float*)d_in[5];
    const float* wX    = (const float*)d_in[6];
    const float* bX    = (const float*)d_in[7];
    float* out = (float*)d_out;

    h16* buf0 = (h16*)d_ws;          // 8.4 MB fp16 ping
    h16* buf1 = (h16*)out;           // fp16 pong inside the (larger) output buffer;
                                     // conv_last reads buf0 only; out fully overwritten.

    conv_first<<<dim3(1024), dim3(256), 0, stream>>>(preop, intra, buf0, w0, b0p);
    for (int i = 0; i < 100; ++i) {
        const h16* src = (i & 1) ? buf1 : buf0;
        h16* dst       = (i & 1) ? buf0 : buf1;
        conv_mid<<<dim3(1024), dim3(256), 0, stream>>>(src, dst, wsp + i * 27, bsp + i);
    }
    conv_last<<<dim3(1024), dim3(256), 0, stream>>>(buf0, out, wX, bX);
}

// Round 13
// 889.456 us; speedup vs baseline: 1.7060x; 1.0376x over previous
//
#include <hip/hip_runtime.h>
#include <math.h>

typedef float nfloat4 __attribute__((ext_vector_type(4), aligned(16)));
typedef float nfloat2 __attribute__((ext_vector_type(2), aligned(8)));
typedef _Float16 h16;
typedef _Float16 h4 __attribute__((ext_vector_type(4)));   // 8B
typedef _Float16 h2 __attribute__((ext_vector_type(2)));   // 4B

__device__ __forceinline__ float softsign(float v) {
    float d = 1.0f + fabsf(v);
    return v * __builtin_amdgcn_rcpf(d);
}
__device__ __forceinline__ void nt_store4(float* p, float a, float b, float c, float d) {
    nfloat4 v; v.x = a; v.y = b; v.z = c; v.w = d;
    __builtin_nontemporal_store(v, (nfloat4*)p);
}
__device__ __forceinline__ void nt_store2(float* p, float a, float b) {
    nfloat2 v; v.x = a; v.y = b;
    __builtin_nontemporal_store(v, (nfloat2*)p);
}
__device__ __forceinline__ int clamp63(int v) { return v < 0 ? 0 : (v > 63 ? 63 : v); }

// -------- first layer: 2 fp32 inputs -> 1 fp16 channel --------
// XCD-AFFINE mapping (new): blk&7 = xcd owns z-slab [8*xcd, 8*xcd+8), matching
// the conv_mid reader mapping -> conv_first's writes land in the L2 that mid#0
// reads from. Per-thread work identical to round-12 (4z x 1y x 4x).
__global__ __launch_bounds__(256) void conv_first(const float* __restrict__ in0,
                                                  const float* __restrict__ in1,
                                                  h16* __restrict__ out,
                                                  const float* __restrict__ w,
                                                  const float* __restrict__ bias) {
    int blk = blockIdx.x;
    int xcd = blk & 7;
    int j   = blk >> 3;                 // 0..127
    int b   = j & 15;
    int z0  = (xcd << 3) + (((j >> 4) & 1) << 2);   // 8*xcd + {0,4}
    int y0  = ((j >> 5) & 3) << 4;                  // 0,16,32,48
    int t = threadIdx.x;
    int xq = (t & 15) << 2;
    int y  = y0 + (t >> 4);

    const float* base0 = in0 + (size_t)b * 262144;
    const float* base1 = in1 + (size_t)b * 262144;

    float acc[4][4];
    #pragma unroll
    for (int i = 0; i < 4; ++i)
        #pragma unroll
        for (int jj = 0; jj < 4; ++jj) acc[i][jj] = 0.0f;

    #pragma unroll
    for (int zi = 0; zi < 6; ++zi) {
        int zin = clamp63(z0 + zi - 1);
        const float* p0 = base0 + zin * 4096;
        const float* p1 = base1 + zin * 4096;
        #pragma unroll
        for (int dy = 0; dy < 3; ++dy) {
            int yin = clamp63(y + dy - 1);
            const float* r0p = p0 + yin * 64;
            const float* r1p = p1 + yin * 64;
            float r0[6], r1[6];
            {
                const float4 v = *(const float4*)(r0p + xq);
                r0[0] = r0p[xq == 0 ? 0 : xq - 1];
                r0[1] = v.x; r0[2] = v.y; r0[3] = v.z; r0[4] = v.w;
                r0[5] = r0p[xq == 60 ? 63 : xq + 4];
            }
            {
                const float4 v = *(const float4*)(r1p + xq);
                r1[0] = r1p[xq == 0 ? 0 : xq - 1];
                r1[1] = v.x; r1[2] = v.y; r1[3] = v.z; r1[4] = v.w;
                r1[5] = r1p[xq == 60 ? 63 : xq + 4];
            }
            #pragma unroll
            for (int dz = 0; dz < 3; ++dz) {
                int zo = zi - dz;
                if (zo >= 0 && zo < 4) {
                    #pragma unroll
                    for (int dx = 0; dx < 3; ++dx) {
                        float w0v = w[dz * 9 + dy * 3 + dx];
                        float w1v = w[27 + dz * 9 + dy * 3 + dx];
                        #pragma unroll
                        for (int xx = 0; xx < 4; ++xx) {
                            acc[zo][xx] = fmaf(w0v, r0[xx + dx], acc[zo][xx]);
                            acc[zo][xx] = fmaf(w1v, r1[xx + dx], acc[zo][xx]);
                        }
                    }
                }
            }
        }
    }
    float bv = *bias;
    h16* obase = out + (size_t)b * 262144 + (size_t)z0 * 4096 + y * 64 + xq;
    #pragma unroll
    for (int zo = 0; zo < 4; ++zo) {
        h4 o;
        o.x = (h16)softsign(acc[zo][0] + bv);
        o.y = (h16)softsign(acc[zo][1] + bv);
        o.z = (h16)softsign(acc[zo][2] + bv);
        o.w = (h16)softsign(acc[zo][3] + bv);
        *(h4*)(obase + zo * 4096) = o;
    }
}

// ---- middle layer, fp16 storage / fp32 math (round-12 verbatim, 922.9 us) ----
#define LROWH   68
#define LPLANEH 680    // 10*68

__global__ __launch_bounds__(256, 4) void conv_mid(const h16* __restrict__ in,
                                                   h16* __restrict__ out,
                                                   const float* __restrict__ w,
                                                   const float* __restrict__ bias) {
    __shared__ h16 lds[10 * LPLANEH];

    int blk = blockIdx.x;
    int xcd = blk & 7;
    int j   = blk >> 3;                // 0..127
    int b   = j & 15;
    int y0  = ((j >> 4) & 7) << 3;     // 0,8,...,56
    int z0  = xcd << 3;                // XCD-affine z-slab

    int t = threadIdx.x;
    int l = t & 15;
    int g = t >> 4;

    const h16* base = in + (size_t)b * 262144;

    float wv[27];
    #pragma unroll
    for (int i = 0; i < 27; ++i) wv[i] = w[i];
    float bv = *bias;

    // ---- stage 100 rows (10 planes x 10 rows); 7 h4 loads/thread ----
    {
        h16* lrows[7]; h4 mv[7];
        #pragma unroll
        for (int it = 0; it < 7; ++it) {
            int rid = it * 16 + g;                 // 0..111 (100..111 dummy)
            int pa = rid / 10;
            pa = pa > 9 ? 9 : pa;                  // dummy rows: clamp-safe addr
            int pr = rid - pa * 10;
            pr = pr > 9 ? 9 : pr;
            const h16* grow = base + clamp63(z0 - 1 + pa) * 4096 + clamp63(y0 - 1 + pr) * 64;
            lrows[it] = &lds[pa * LPLANEH + pr * LROWH];
            mv[it] = *(const h4*)(grow + 4 * l);   // 8B-aligned; l==15 holds x=60..63
        }
        #pragma unroll
        for (int it = 0; it < 7; ++it) {
            int rid = it * 16 + g;
            if (rid < 100) {
                *(h4*)(lrows[it] + 4 * l) = mv[it];
                if (l == 15) {                      // dup x=63 into slots 64,65
                    h2 d; d.x = mv[it].w; d.y = mv[it].w;
                    *(h2*)(lrows[it] + 64) = d;
                }
            }
        }
    }
    __syncthreads();

    // ---- compute (fp32 math): 4z x 1y x 4x per thread ----
    int xq   = l << 2;
    int yloc = g & 7;              // 0..7; LDS rows yloc..yloc+2 = y-1,y,y+1
    int zh   = (g >> 3) << 2;      // 0 or 4

    float acc[4][4];
    #pragma unroll
    for (int i = 0; i < 4; ++i)
        #pragma unroll
        for (int k = 0; k < 4; ++k) acc[i][k] = 0.0f;

    #pragma unroll
    for (int pp = 0; pp < 6; ++pp) {
        const h16* pl = &lds[(zh + pp) * LPLANEH];
        #pragma unroll
        for (int dy = 0; dy < 3; ++dy) {
            const h16* lrow = pl + (yloc + dy) * LROWH;
            h4 v  = *(const h4*)(lrow + xq);
            h2 v2 = *(const h2*)(lrow + xq + 4);
            h2 vf = *(const h2*)(lrow + (xq == 0 ? 0 : xq - 2));
            float r[6];
            r[0] = (xq == 0) ? (float)v.x : (float)vf.y;
            r[1] = (float)v.x; r[2] = (float)v.y; r[3] = (float)v.z;
            r[4] = (float)v.w; r[5] = (float)v2.x;
            #pragma unroll
            for (int dz = 0; dz < 3; ++dz) {
                int zz = pp - dz;
                if (zz >= 0 && zz < 4) {
                    #pragma unroll
                    for (int dx = 0; dx < 3; ++dx) {
                        float ww = wv[dz * 9 + dy * 3 + dx];
                        #pragma unroll
                        for (int xx = 0; xx < 4; ++xx)
                            acc[zz][xx] = fmaf(ww, r[xx + dx], acc[zz][xx]);
                    }
                }
            }
        }
    }

    int y = y0 + yloc;
    h16* obase = out + (size_t)b * 262144 + (size_t)(z0 + zh) * 4096 + y * 64 + xq;
    #pragma unroll
    for (int zz = 0; zz < 4; ++zz) {
        h4 o;
        o.x = (h16)softsign(acc[zz][0] + bv);
        o.y = (h16)softsign(acc[zz][1] + bv);
        o.z = (h16)softsign(acc[zz][2] + bv);
        o.w = (h16)softsign(acc[zz][3] + bv);
        *(h4*)(obase + zz * 4096) = o;   // normal store: stays in local-XCD L2
    }
}

// -------- last layer: fp16 in -> 3 fp32 channels + strided downsamples --------
// XCD-AFFINE mapping (new): blk&7 = xcd reads z in [8*xcd-1, 8*xcd+8] -- the
// slab mid#99's xcd-affine writers left dirty in THIS XCD's L2 (was: flat tid
// mapping -> ~7/8 cross-XCD remote-L2 snoops -> 44.5 us latency-bound kernel).
// Per-thread work and all store addressing identical to round-12; r32's two
// scalar nt-stores merged into one 8B float2 nt-store (adjacent, 8B-aligned).
__device__ __forceinline__ void load_row6h(const h16* __restrict__ row, int x0, float r[6]) {
    h4 v = *(const h4*)(row + x0);
    r[0] = (float)row[x0 == 0 ? 0 : x0 - 1];
    r[1] = (float)v.x; r[2] = (float)v.y; r[3] = (float)v.z; r[4] = (float)v.w;
    r[5] = (float)row[x0 == 60 ? 63 : x0 + 4];
}

__global__ __launch_bounds__(256) void conv_last(const h16* __restrict__ in,
                                                 float* __restrict__ out,
                                                 const float* __restrict__ w,
                                                 const float* __restrict__ bias) {
    int blk = blockIdx.x;
    int xcd = blk & 7;
    int j   = blk >> 3;                 // 0..127
    int b   = j & 15;
    int z0  = (xcd << 3) + (((j >> 4) & 1) << 2);   // 8*xcd + {0,4}
    int y0  = ((j >> 5) & 3) << 4;                  // 0,16,32,48
    int t = threadIdx.x;
    int xq = (t & 15) << 2;
    int y  = y0 + (t >> 4);

    const h16* base = in + (size_t)b * 262144;

    float acc[4][3][4];
    #pragma unroll
    for (int i = 0; i < 4; ++i)
        #pragma unroll
        for (int c = 0; c < 3; ++c)
            #pragma unroll
            for (int jj = 0; jj < 4; ++jj) acc[i][c][jj] = 0.0f;

    #pragma unroll
    for (int zi = 0; zi < 6; ++zi) {
        int zin = clamp63(z0 + zi - 1);
        const h16* plane = base + zin * 4096;
        #pragma unroll
        for (int dy = 0; dy < 3; ++dy) {
            int yin = clamp63(y + dy - 1);
            float r[6];
            load_row6h(plane + yin * 64, xq, r);
            #pragma unroll
            for (int dz = 0; dz < 3; ++dz) {
                int zo = zi - dz;
                if (zo >= 0 && zo < 4) {
                    #pragma unroll
                    for (int c = 0; c < 3; ++c) {
                        #pragma unroll
                        for (int dx = 0; dx < 3; ++dx) {
                            float wc = w[c * 27 + dz * 9 + dy * 3 + dx];
                            #pragma unroll
                            for (int xx = 0; xx < 4; ++xx)
                                acc[zo][c][xx] = fmaf(wc, r[xx + dx], acc[zo][c][xx]);
                        }
                    }
                }
            }
        }
    }

    float* r64 = out;
    float* r32 = out + 12582912;
    float* r16 = r32 + 1572864;
    float* r8  = r16 + 196608;

    float vals[4][3][4];
    #pragma unroll
    for (int zo = 0; zo < 4; ++zo)
        #pragma unroll
        for (int c = 0; c < 3; ++c) {
            float bv = bias[c];
            #pragma unroll
            for (int xx = 0; xx < 4; ++xx)
                vals[zo][c][xx] = softsign(acc[zo][c][xx] + bv);
        }

    #pragma unroll
    for (int c = 0; c < 3; ++c) {
        float* cb = r64 + ((size_t)b * 3 + c) * 262144 + (size_t)z0 * 4096 + y * 64 + xq;
        #pragma unroll
        for (int zo = 0; zo < 4; ++zo) {
            nt_store4(cb + zo * 4096,
                      vals[zo][c][0], vals[zo][c][1], vals[zo][c][2], vals[zo][c][3]);
        }
    }
    if ((y & 1) == 0) {
        #pragma unroll
        for (int c = 0; c < 3; ++c) {
            size_t cb = ((size_t)b * 3 + c) * 32768 + (size_t)(y >> 1) * 32;
            #pragma unroll
            for (int zo = 0; zo < 4; zo += 2) {
                size_t zb = cb + (size_t)((z0 + zo) >> 1) * 1024;
                nt_store2(r32 + zb + (xq >> 1), vals[zo][c][0], vals[zo][c][2]);
            }
        }
    }
    if ((y & 3) == 0) {
        #pragma unroll
        for (int c = 0; c < 3; ++c) {
            __builtin_nontemporal_store(vals[0][c][0],
                r16 + ((size_t)b * 3 + c) * 4096 + (size_t)(z0 >> 2) * 256 + (y >> 2) * 16 + (xq >> 2));
        }
    }
    if ((y & 7) == 0 && (z0 & 7) == 0 && (xq & 7) == 0) {
        #pragma unroll
        for (int c = 0; c < 3; ++c) {
            __builtin_nontemporal_store(vals[0][c][0],
                r8 + ((size_t)b * 3 + c) * 512 + (size_t)(z0 >> 3) * 64 + (y >> 3) * 8 + (xq >> 3));
        }
    }
}

extern "C" void kernel_launch(void* const* d_in, const int* in_sizes, int n_in,
                              void* d_out, int out_size, void* d_ws, size_t ws_size,
                              hipStream_t stream) {
    const float* preop = (const float*)d_in[0];
    const float* intra = (const float*)d_in[1];
    const float* w0    = (const float*)d_in[2];
    const float* b0p   = (const float*)d_in[3];
    const float* wsp   = (const float*)d_in[4];
    const float* bsp   = (const float*)d_in[5];
    const float* wX    = (const float*)d_in[6];
    const float* bX    = (const float*)d_in[7];
    float* out = (float*)d_out;

    h16* buf0 = (h16*)d_ws;          // 8.4 MB fp16 ping
    h16* buf1 = (h16*)out;           // fp16 pong inside the (larger) output buffer;
                                     // conv_last reads buf0 only; out fully overwritten.

    conv_first<<<dim3(1024), dim3(256), 0, stream>>>(preop, intra, buf0, w0, b0p);
    for (int i = 0; i < 100; ++i) {
        const h16* src = (i & 1) ? buf1 : buf0;
        h16* dst       = (i & 1) ? buf0 : buf1;
        conv_mid<<<dim3(1024), dim3(256), 0, stream>>>(src, dst, wsp + i * 27, bsp + i);
    }
    conv_last<<<dim3(1024), dim3(256), 0, stream>>>(buf0, out, wX, bX);
}